// Round 5
// baseline (3061.100 us; speedup 1.0000x reference)
//
#include <hip/hip_runtime.h>

#define NN 100000
#define NE 3200000
#define NCH 6
#define D_IN 256
#define D_H 16
#define RB 256                    // rows per bucket
#define NB 392                    // buckets per channel (392*256 = 100352 >= NN)
#define NBT (NB * NCH)            // 2352 total buckets
#define CAP 16                    // staging ring entries per bucket

typedef float vf4 __attribute__((ext_vector_type(4)));

// ---- workspace layout (bytes) ----
static constexpr size_t OFF_H     = 0;                      // bf16 [C][N][16] = 19,200,000
static constexpr size_t OFF_CNT   = 19200000;               // u32 [NBT] = 9408
static constexpr size_t OFF_START = OFF_CNT + 9408;
static constexpr size_t OFF_CURS  = OFF_START + 9408;
static constexpr size_t OFF_PAYA  = 19228224;               // 64B aligned; u32 [19,237,632]
static constexpr size_t OFF_PAYB  = OFF_PAYA + 76950528;    // 64B aligned; u16
// total ~134.7 MB

static __device__ __forceinline__ unsigned short f2bf(float f) {
    union { float f; unsigned int u; } v; v.f = f;
    unsigned int u = v.u;
    unsigned int r = (u + 0x7FFFu + ((u >> 16) & 1u)) >> 16;  // RNE
    return (unsigned short)r;
}
static __device__ __forceinline__ float bf2f(unsigned int s16) {
    union { unsigned int u; float f; } v; v.u = s16 << 16; return v.f;
}

// ---------------- projection: h[c][n][16] (bf16) = x[n][:] . W[c][:][:] ----------
__global__ __launch_bounds__(256) void proj_kernel(const float* __restrict__ x,
                                                   const float* __restrict__ W,
                                                   unsigned short* __restrict__ h) {
    int n = blockIdx.x * 256 + threadIdx.x;
    if (n >= NN) return;
    const float* xr = x + (size_t)n * D_IN;

    float acc[96];
#pragma unroll
    for (int i = 0; i < 96; ++i) acc[i] = 0.f;

#pragma unroll 1
    for (int d4 = 0; d4 < D_IN / 4; ++d4) {
        float4 xv = reinterpret_cast<const float4*>(xr)[d4];
#pragma unroll
        for (int dd = 0; dd < 4; ++dd) {
            float xs = (&xv.x)[dd];
            int d = d4 * 4 + dd;
#pragma unroll
            for (int c = 0; c < NCH; ++c) {
#pragma unroll
                for (int hh = 0; hh < D_H; ++hh) {
                    acc[c * 16 + hh] = fmaf(xs, W[c * (D_IN * D_H) + d * D_H + hh],
                                            acc[c * 16 + hh]);
                }
            }
        }
    }

#pragma unroll
    for (int c = 0; c < NCH; ++c) {
        unsigned int w[8];
#pragma unroll
        for (int j = 0; j < 8; ++j) {
            unsigned int lo = f2bf(acc[c * 16 + 2 * j + 0]);
            unsigned int hi = f2bf(acc[c * 16 + 2 * j + 1]);
            w[j] = lo | (hi << 16);
        }
        uint4* dst = reinterpret_cast<uint4*>(h + ((size_t)c * NN + n) * 16);
        dst[0] = make_uint4(w[0], w[1], w[2], w[3]);
        dst[1] = make_uint4(w[4], w[5], w[6], w[7]);
    }
}

// ---------------- bucket histogram (LDS-staged) ----------------
#define H_EPB 4096
__global__ __launch_bounds__(256) void bhist_kernel(const int* __restrict__ rows,
                                                    unsigned int* __restrict__ counts) {
    __shared__ unsigned int sh[NB];
    int c = blockIdx.y;
    int tid = threadIdx.x;
    for (int i = tid; i < NB; i += 256) sh[i] = 0u;
    __syncthreads();
    size_t e0 = (size_t)blockIdx.x * H_EPB;
    size_t e1 = e0 + H_EPB; if (e1 > NE) e1 = NE;
    const int* rp = rows + (size_t)c * NE;
    for (size_t e = e0 + tid; e < e1; e += 256) {
        int r = rp[e];
        atomicAdd(&sh[r >> 8], 1u);
    }
    __syncthreads();
    for (int i = tid; i < NB; i += 256)
        if (sh[i]) atomicAdd(&counts[c * NB + i], sh[i]);
}

// ---------------- scan: 16-padded exclusive starts + cursors (1 block, 4/thread) ----
__global__ __launch_bounds__(1024) void bscan_kernel(const unsigned int* __restrict__ counts,
                                                     unsigned int* __restrict__ starts,
                                                     unsigned int* __restrict__ cursors) {
    __shared__ unsigned int s[1024];
    int t = threadIdx.x;
    unsigned int a[4]; unsigned int sum = 0u;
#pragma unroll
    for (int j = 0; j < 4; ++j) {
        int i = 4 * t + j;
        a[j] = (i < NBT) ? ((counts[i] + 15u) & ~15u) : 0u;
        sum += a[j];
    }
    s[t] = sum;
    __syncthreads();
#pragma unroll
    for (int off = 1; off < 1024; off <<= 1) {
        unsigned int v = (t >= off) ? s[t - off] : 0u;
        __syncthreads();
        s[t] += v;
        __syncthreads();
    }
    unsigned int excl = s[t] - sum;
#pragma unroll
    for (int j = 0; j < 4; ++j) {
        int i = 4 * t + j;
        if (i < NBT) { starts[i] = excl; cursors[i] = excl; }
        excl += a[j];
    }
}

// ---------------- binning: edges -> (c,bucket) segments, coalesced flushes ----------
#define B_EPB 12500   // 256 blocks/channel
__global__ __launch_bounds__(256) void bin_kernel(const int* __restrict__ rows,
                                                  const int* __restrict__ cols,
                                                  const float* __restrict__ vals,
                                                  unsigned int* __restrict__ cursors,
                                                  unsigned int* __restrict__ payA,
                                                  unsigned short* __restrict__ payB) {
    __shared__ unsigned int   sA[NB * CAP];     // 25088 B
    __shared__ unsigned short sB[NB * CAP];     // 12544 B
    __shared__ unsigned int   scnt[NB];
    __shared__ unsigned int   sflush[NB];

    int c = blockIdx.y;
    int tid = threadIdx.x;
    for (int i = tid; i < NB; i += 256) { scnt[i] = 0u; sflush[i] = 0u; }
    __syncthreads();

    size_t e0 = (size_t)blockIdx.x * B_EPB;
    size_t e1 = e0 + B_EPB; if (e1 > NE) e1 = NE;
    const int*   rp = rows + (size_t)c * NE;
    const int*   cp = cols + (size_t)c * NE;
    const float* vp = vals + (size_t)c * NE;

    for (size_t base = e0; base < e1; base += 256) {
        size_t e = base + tid;
        if (e < e1) {
            int r = rp[e];
            unsigned int col = (unsigned int)cp[e];
            float v = vp[e];
            unsigned int q = (unsigned int)(v * 65535.0f + 0.5f);
            if (q > 65535u) q = 65535u;
            int b = r >> 8;
            unsigned int pa = (col << 8) | (unsigned int)(r & (RB - 1));
            unsigned int pos = atomicAdd(&scnt[b], 1u);
            if (pos - sflush[b] < CAP) {
                sA[b * CAP + (pos & (CAP - 1))] = pa;
                sB[b * CAP + (pos & (CAP - 1))] = (unsigned short)q;
            } else {
                // rare ring overflow: undo count, write direct
                atomicSub(&scnt[b], 1u);
                unsigned int g = atomicAdd(&cursors[c * NB + b], 1u);
                payA[g] = pa;
                payB[g] = (unsigned short)q;
            }
        }
        __syncthreads();
        // flush full 16-entry chunks (threads stride over buckets)
        for (int bb = tid; bb < NB; bb += 256) {
            unsigned int cnt = scnt[bb], fl = sflush[bb];
            unsigned int n = (cnt - fl) & ~15u;
            if (n) {
                unsigned int g = atomicAdd(&cursors[c * NB + bb], n);
                for (unsigned int i = 0; i < n; i += 16) {
                    unsigned int slot = (fl + i) & (CAP - 1);   // 0 with CAP=16
                    if ((g & 15u) == 0u) {
#pragma unroll
                        for (int k = 0; k < 4; ++k) {
                            uint4 va = *reinterpret_cast<uint4*>(&sA[bb * CAP + slot + 4 * k]);
                            *reinterpret_cast<uint4*>(&payA[g + i + 4 * k]) = va;
                        }
#pragma unroll
                        for (int k = 0; k < 2; ++k) {
                            uint4 vb = *reinterpret_cast<uint4*>(&sB[bb * CAP + slot + 8 * k]);
                            *reinterpret_cast<uint4*>(&payB[g + i + 8 * k]) = vb;
                        }
                    } else {
#pragma unroll
                        for (int k = 0; k < 16; ++k) {
                            payA[g + i + k] = sA[bb * CAP + slot + k];
                            payB[g + i + k] = sB[bb * CAP + slot + k];
                        }
                    }
                }
                sflush[bb] = fl + n;
            }
        }
        __syncthreads();
    }
    // final drain of partial chunks
    for (int bb = tid; bb < NB; bb += 256) {
        unsigned int cnt = scnt[bb], fl = sflush[bb];
        unsigned int n = cnt - fl;
        if (n) {
            unsigned int g = atomicAdd(&cursors[c * NB + bb], n);
            for (unsigned int i = 0; i < n; ++i) {
                unsigned int slot = (fl + i) & (CAP - 1);
                payA[g + i] = sA[bb * CAP + slot];
                payB[g + i] = sB[bb * CAP + slot];
            }
        }
    }
}

// ---------------- accumulate (one channel per launch -> h slice L2-resident) ------
__global__ __launch_bounds__(256) void accum_kernel(int c,
                                                    const unsigned int* __restrict__ starts,
                                                    const unsigned int* __restrict__ counts,
                                                    const unsigned int* __restrict__ payA,
                                                    const unsigned short* __restrict__ payB,
                                                    const unsigned short* __restrict__ h,
                                                    const float* __restrict__ bias,
                                                    float* __restrict__ out) {
    __shared__ float acc[RB * 17];   // 17408 B; stride 17 breaks bank aliasing
    int b = blockIdx.x;
    int cb = c * NB + b;
    int tid = threadIdx.x;

    for (int i = tid; i < RB * 17; i += 256) acc[i] = 0.f;
    __syncthreads();

    unsigned int start = starts[cb];
    unsigned int cnt = counts[cb];
    const unsigned short* hc = h + (size_t)c * NN * 16;

    // 4-edge ILP batches: 4 gathers in flight per thread before the atomic block
    for (unsigned int base = 0; base < cnt; base += 1024) {
        unsigned int paL[4];
        float vL[4];
        uint4 g0[4], g1[4];
#pragma unroll
        for (int i = 0; i < 4; ++i) {
            unsigned int k = base + tid + (unsigned int)i * 256u;
            unsigned int kk = (k < cnt) ? k : 0u;
            unsigned int pa = __builtin_nontemporal_load(payA + start + kk);
            unsigned short pb = __builtin_nontemporal_load(payB + start + kk);
            paL[i] = pa;
            vL[i] = (k < cnt) ? (float)pb * (1.0f / 65535.0f) : 0.f;
            const uint4* hp = reinterpret_cast<const uint4*>(hc + (size_t)(pa >> 8) * 16);
            g0[i] = hp[0];
            g1[i] = hp[1];
        }
#pragma unroll
        for (int i = 0; i < 4; ++i) {
            float v = vL[i];
            float* ap = &acc[(paL[i] & (RB - 1u)) * 17];
            const unsigned int* w0 = &g0[i].x;
            const unsigned int* w1 = &g1[i].x;
#pragma unroll
            for (int j = 0; j < 4; ++j) {
                unsigned int w = w0[j];
                atomicAdd(ap + 2 * j + 0, v * bf2f(w & 0xFFFFu));
                atomicAdd(ap + 2 * j + 1, v * bf2f(w >> 16));
            }
#pragma unroll
            for (int j = 0; j < 4; ++j) {
                unsigned int w = w1[j];
                atomicAdd(ap + 8 + 2 * j + 0, v * bf2f(w & 0xFFFFu));
                atomicAdd(ap + 8 + 2 * j + 1, v * bf2f(w >> 16));
            }
        }
    }
    __syncthreads();

    // epilogue: out[r][c*16 + j] = relu(acc + bias)
    int rbase = b * RB;
    for (int idx = tid; idx < RB * 4; idx += 256) {
        int r9 = idx >> 2;
        int j4 = (idx & 3) * 4;
        int r = rbase + r9;
        if (r >= NN) continue;
        const float* ap = &acc[r9 * 17 + j4];
        vf4 o;
        o.x = fmaxf(ap[0] + bias[c * 16 + j4 + 0], 0.f);
        o.y = fmaxf(ap[1] + bias[c * 16 + j4 + 1], 0.f);
        o.z = fmaxf(ap[2] + bias[c * 16 + j4 + 2], 0.f);
        o.w = fmaxf(ap[3] + bias[c * 16 + j4 + 3], 0.f);
        __builtin_nontemporal_store(o, reinterpret_cast<vf4*>(&out[(size_t)r * 96 + c * 16 + j4]));
    }
}

extern "C" void kernel_launch(void* const* d_in, const int* in_sizes, int n_in,
                              void* d_out, int out_size, void* d_ws, size_t ws_size,
                              hipStream_t stream) {
    const float* x         = (const float*)d_in[0];
    const float* W         = (const float*)d_in[1];
    const float* b         = (const float*)d_in[2];
    const float* edge_vals = (const float*)d_in[3];
    const int*   edge_rows = (const int*)d_in[4];
    const int*   edge_cols = (const int*)d_in[5];
    float* out = (float*)d_out;

    char* ws = (char*)d_ws;
    unsigned short* h       = (unsigned short*)(ws + OFF_H);
    unsigned int*   counts  = (unsigned int*)(ws + OFF_CNT);
    unsigned int*   starts  = (unsigned int*)(ws + OFF_START);
    unsigned int*   cursors = (unsigned int*)(ws + OFF_CURS);
    unsigned int*   payA    = (unsigned int*)(ws + OFF_PAYA);
    unsigned short* payB    = (unsigned short*)(ws + OFF_PAYB);

    (void)hipMemsetAsync(counts, 0, NBT * sizeof(unsigned int), stream);

    proj_kernel<<<(NN + 255) / 256, 256, 0, stream>>>(x, W, h);

    dim3 gh((NE + H_EPB - 1) / H_EPB, NCH);
    bhist_kernel<<<gh, 256, 0, stream>>>(edge_rows, counts);

    bscan_kernel<<<1, 1024, 0, stream>>>(counts, starts, cursors);

    dim3 gb((NE + B_EPB - 1) / B_EPB, NCH);
    bin_kernel<<<gb, 256, 0, stream>>>(edge_rows, edge_cols, edge_vals, cursors, payA, payB);

    for (int c = 0; c < NCH; ++c)
        accum_kernel<<<NB, 256, 0, stream>>>(c, starts, counts, payA, payB, h, b, out);
}

// Round 6
// 2389.510 us; speedup vs baseline: 1.2811x; 1.2811x over previous
//
#include <hip/hip_runtime.h>

#define NN 100000
#define NE 3200000
#define NCH 6
#define D_IN 256
#define D_H 16
#define RB 256                    // rows per bucket
#define NB 392                    // buckets per channel (392*256 = 100352 >= NN)
#define NBT (NB * NCH)            // 2352 total buckets
#define CAP 16                    // staging ring entries per bucket

typedef float vf4 __attribute__((ext_vector_type(4)));

// ---- workspace layout (bytes) ----
static constexpr size_t OFF_H     = 0;                      // bf16 [C][N][16] = 19,200,000
static constexpr size_t OFF_CNT   = 19200000;               // u32 [NBT] = 9408
static constexpr size_t OFF_START = OFF_CNT + 9408;
static constexpr size_t OFF_CURS  = OFF_START + 9408;
static constexpr size_t OFF_PAYA  = 19228224;               // 64B aligned; u32
static constexpr size_t OFF_PAYB  = OFF_PAYA + 76950528;    // 64B aligned; u16
// total ~134.7 MB

static __device__ __forceinline__ unsigned short f2bf(float f) {
    union { float f; unsigned int u; } v; v.f = f;
    unsigned int u = v.u;
    unsigned int r = (u + 0x7FFFu + ((u >> 16) & 1u)) >> 16;  // RNE
    return (unsigned short)r;
}
static __device__ __forceinline__ float bf2f(unsigned int s16) {
    union { unsigned int u; float f; } v; v.u = s16 << 16; return v.f;
}

// ---------------- projection: h[c][n][16] (bf16) = x[n][:] . W[c][:][:] ----------
__global__ __launch_bounds__(256) void proj_kernel(const float* __restrict__ x,
                                                   const float* __restrict__ W,
                                                   unsigned short* __restrict__ h) {
    int n = blockIdx.x * 256 + threadIdx.x;
    if (n >= NN) return;
    const float* xr = x + (size_t)n * D_IN;

    float acc[96];
#pragma unroll
    for (int i = 0; i < 96; ++i) acc[i] = 0.f;

#pragma unroll 1
    for (int d4 = 0; d4 < D_IN / 4; ++d4) {
        float4 xv = reinterpret_cast<const float4*>(xr)[d4];
#pragma unroll
        for (int dd = 0; dd < 4; ++dd) {
            float xs = (&xv.x)[dd];
            int d = d4 * 4 + dd;
#pragma unroll
            for (int c = 0; c < NCH; ++c) {
#pragma unroll
                for (int hh = 0; hh < D_H; ++hh) {
                    acc[c * 16 + hh] = fmaf(xs, W[c * (D_IN * D_H) + d * D_H + hh],
                                            acc[c * 16 + hh]);
                }
            }
        }
    }

#pragma unroll
    for (int c = 0; c < NCH; ++c) {
        unsigned int w[8];
#pragma unroll
        for (int j = 0; j < 8; ++j) {
            unsigned int lo = f2bf(acc[c * 16 + 2 * j + 0]);
            unsigned int hi = f2bf(acc[c * 16 + 2 * j + 1]);
            w[j] = lo | (hi << 16);
        }
        uint4* dst = reinterpret_cast<uint4*>(h + ((size_t)c * NN + n) * 16);
        dst[0] = make_uint4(w[0], w[1], w[2], w[3]);
        dst[1] = make_uint4(w[4], w[5], w[6], w[7]);
    }
}

// ---------------- bucket histogram (LDS-staged) ----------------
#define H_EPB 4096
__global__ __launch_bounds__(256) void bhist_kernel(const int* __restrict__ rows,
                                                    unsigned int* __restrict__ counts) {
    __shared__ unsigned int sh[NB];
    int c = blockIdx.y;
    int tid = threadIdx.x;
    for (int i = tid; i < NB; i += 256) sh[i] = 0u;
    __syncthreads();
    size_t e0 = (size_t)blockIdx.x * H_EPB;
    size_t e1 = e0 + H_EPB; if (e1 > NE) e1 = NE;
    const int* rp = rows + (size_t)c * NE;
    for (size_t e = e0 + tid; e < e1; e += 256) {
        int r = rp[e];
        atomicAdd(&sh[r >> 8], 1u);
    }
    __syncthreads();
    for (int i = tid; i < NB; i += 256)
        if (sh[i]) atomicAdd(&counts[c * NB + i], sh[i]);
}

// ---------------- scan: 16-padded exclusive starts + cursors (1 block, 4/thread) ----
__global__ __launch_bounds__(1024) void bscan_kernel(const unsigned int* __restrict__ counts,
                                                     unsigned int* __restrict__ starts,
                                                     unsigned int* __restrict__ cursors) {
    __shared__ unsigned int s[1024];
    int t = threadIdx.x;
    unsigned int a[4]; unsigned int sum = 0u;
#pragma unroll
    for (int j = 0; j < 4; ++j) {
        int i = 4 * t + j;
        a[j] = (i < NBT) ? ((counts[i] + 15u) & ~15u) : 0u;
        sum += a[j];
    }
    s[t] = sum;
    __syncthreads();
#pragma unroll
    for (int off = 1; off < 1024; off <<= 1) {
        unsigned int v = (t >= off) ? s[t - off] : 0u;
        __syncthreads();
        s[t] += v;
        __syncthreads();
    }
    unsigned int excl = s[t] - sum;
#pragma unroll
    for (int j = 0; j < 4; ++j) {
        int i = 4 * t + j;
        if (i < NBT) { starts[i] = excl; cursors[i] = excl; }
        excl += a[j];
    }
}

// ---------------- binning: edges -> (c,bucket) segments, coalesced flushes ----------
#define B_EPB 12544   // 256 blocks/channel; multiple of 512
__global__ __launch_bounds__(256) void bin_kernel(const int* __restrict__ rows,
                                                  const int* __restrict__ cols,
                                                  const float* __restrict__ vals,
                                                  unsigned int* __restrict__ cursors,
                                                  unsigned int* __restrict__ payA,
                                                  unsigned short* __restrict__ payB) {
    __shared__ unsigned int   sA[NB * CAP];     // 25088 B
    __shared__ unsigned short sB[NB * CAP];     // 12544 B
    __shared__ unsigned int   scnt[NB];
    __shared__ unsigned int   sflush[NB];

    int c = blockIdx.y;
    int tid = threadIdx.x;
    for (int i = tid; i < NB; i += 256) { scnt[i] = 0u; sflush[i] = 0u; }
    __syncthreads();

    size_t e0 = (size_t)blockIdx.x * B_EPB;
    size_t e1 = e0 + B_EPB; if (e1 > NE) e1 = NE;
    const int*   rp = rows + (size_t)c * NE;
    const int*   cp = cols + (size_t)c * NE;
    const float* vp = vals + (size_t)c * NE;

    for (size_t base = e0; base < e1; base += 512) {
#pragma unroll
        for (int half = 0; half < 2; ++half) {
            size_t e = base + (size_t)half * 256 + tid;
            if (e < e1) {
                int r = rp[e];
                unsigned int col = (unsigned int)cp[e];
                float v = vp[e];
                unsigned int q = (unsigned int)(v * 65535.0f + 0.5f);
                if (q > 65535u) q = 65535u;
                int b = r >> 8;
                unsigned int pa = (col << 8) | (unsigned int)(r & (RB - 1));
                unsigned int pos = atomicAdd(&scnt[b], 1u);
                if (pos - sflush[b] < CAP) {
                    sA[b * CAP + (pos & (CAP - 1))] = pa;
                    sB[b * CAP + (pos & (CAP - 1))] = (unsigned short)q;
                } else {
                    // rare ring overflow: undo count, write direct
                    atomicSub(&scnt[b], 1u);
                    unsigned int g = atomicAdd(&cursors[c * NB + b], 1u);
                    payA[g] = pa;
                    payB[g] = (unsigned short)q;
                }
            }
            __syncthreads();
            // flush full 16-entry chunks (threads stride over buckets)
            for (int bb = tid; bb < NB; bb += 256) {
                unsigned int cnt = scnt[bb], fl = sflush[bb];
                unsigned int n = (cnt - fl) & ~15u;
                if (n) {
                    unsigned int g = atomicAdd(&cursors[c * NB + bb], n);
                    for (unsigned int i = 0; i < n; i += 16) {
                        unsigned int slot = (fl + i) & (CAP - 1);   // 0 with CAP=16
                        if ((g & 15u) == 0u) {
#pragma unroll
                            for (int k = 0; k < 4; ++k) {
                                uint4 va = *reinterpret_cast<uint4*>(&sA[bb * CAP + slot + 4 * k]);
                                *reinterpret_cast<uint4*>(&payA[g + i + 4 * k]) = va;
                            }
#pragma unroll
                            for (int k = 0; k < 2; ++k) {
                                uint4 vb = *reinterpret_cast<uint4*>(&sB[bb * CAP + slot + 8 * k]);
                                *reinterpret_cast<uint4*>(&payB[g + i + 8 * k]) = vb;
                            }
                        } else {
#pragma unroll
                            for (int k = 0; k < 16; ++k) {
                                payA[g + i + k] = sA[bb * CAP + slot + k];
                                payB[g + i + k] = sB[bb * CAP + slot + k];
                            }
                        }
                    }
                    sflush[bb] = fl + n;
                }
            }
            __syncthreads();
        }
    }
    // final drain of partial chunks
    for (int bb = tid; bb < NB; bb += 256) {
        unsigned int cnt = scnt[bb], fl = sflush[bb];
        unsigned int n = cnt - fl;
        if (n) {
            unsigned int g = atomicAdd(&cursors[c * NB + bb], n);
            for (unsigned int i = 0; i < n; ++i) {
                unsigned int slot = (fl + i) & (CAP - 1);
                payA[g + i] = sA[bb * CAP + slot];
                payB[g + i] = sB[bb * CAP + slot];
            }
        }
    }
}

// ---------------- accumulate: 16 lanes per edge, fused over all channels ----------
// lane = (group g = tid>>4, elem j = tid&15). Group handles one edge:
// 32B contiguous h-gather shared by 16 lanes (1 L1 transaction per edge),
// one conflict-free ds_add per lane.
__global__ __launch_bounds__(256, 8) void accum_kernel(
        const unsigned int* __restrict__ starts,
        const unsigned int* __restrict__ counts,
        const unsigned int* __restrict__ payA,
        const unsigned short* __restrict__ payB,
        const unsigned short* __restrict__ h,
        const float* __restrict__ bias,
        float* __restrict__ out) {
    __shared__ float acc[RB * 17];   // 17408 B; stride 17 breaks bank aliasing
    int cb = blockIdx.x;             // cb = c*NB + b
    int c = cb / NB;
    int b = cb - c * NB;
    int tid = threadIdx.x;
    int g = tid >> 4;                // 0..15 edge-group within block
    int j = tid & 15;                // element index

    for (int i = tid; i < RB * 17; i += 256) acc[i] = 0.f;
    __syncthreads();

    unsigned int start = starts[cb];
    unsigned int cnt = counts[cb];
    const unsigned short* hc = h + (size_t)c * NN * 16;

    // 64 edges per block-iteration (16 groups x ILP4), 4 gather chains in flight
    for (unsigned int base = 0; base < cnt; base += 64) {
        float hv[4], vv[4];
        unsigned int rr[4];
#pragma unroll
        for (int i = 0; i < 4; ++i) {
            unsigned int k = base + (unsigned int)g + (unsigned int)i * 16u;
            unsigned int kk = (k < cnt) ? k : 0u;
            unsigned int pa = __builtin_nontemporal_load(payA + start + kk);
            unsigned short q = __builtin_nontemporal_load(payB + start + kk);
            rr[i] = pa & (RB - 1u);
            vv[i] = (k < cnt) ? (float)q * (1.0f / 65535.0f) : 0.f;
            hv[i] = bf2f(hc[(size_t)(pa >> 8) * 16 + j]);
        }
#pragma unroll
        for (int i = 0; i < 4; ++i) {
            atomicAdd(&acc[rr[i] * 17 + j], vv[i] * hv[i]);
        }
    }
    __syncthreads();

    // epilogue: thread tid owns row rbase+tid -> 64B output line
    int r = b * RB + tid;
    if (r < NN) {
        const float* ap = &acc[tid * 17];
        const float* bc = bias + c * 16;
#pragma unroll
        for (int gi = 0; gi < 4; ++gi) {
            vf4 o;
            o.x = fmaxf(ap[4 * gi + 0] + bc[4 * gi + 0], 0.f);
            o.y = fmaxf(ap[4 * gi + 1] + bc[4 * gi + 1], 0.f);
            o.z = fmaxf(ap[4 * gi + 2] + bc[4 * gi + 2], 0.f);
            o.w = fmaxf(ap[4 * gi + 3] + bc[4 * gi + 3], 0.f);
            __builtin_nontemporal_store(o, reinterpret_cast<vf4*>(&out[(size_t)r * 96 + c * 16 + gi * 4]));
        }
    }
}

extern "C" void kernel_launch(void* const* d_in, const int* in_sizes, int n_in,
                              void* d_out, int out_size, void* d_ws, size_t ws_size,
                              hipStream_t stream) {
    const float* x         = (const float*)d_in[0];
    const float* W         = (const float*)d_in[1];
    const float* b         = (const float*)d_in[2];
    const float* edge_vals = (const float*)d_in[3];
    const int*   edge_rows = (const int*)d_in[4];
    const int*   edge_cols = (const int*)d_in[5];
    float* out = (float*)d_out;

    char* ws = (char*)d_ws;
    unsigned short* h       = (unsigned short*)(ws + OFF_H);
    unsigned int*   counts  = (unsigned int*)(ws + OFF_CNT);
    unsigned int*   starts  = (unsigned int*)(ws + OFF_START);
    unsigned int*   cursors = (unsigned int*)(ws + OFF_CURS);
    unsigned int*   payA    = (unsigned int*)(ws + OFF_PAYA);
    unsigned short* payB    = (unsigned short*)(ws + OFF_PAYB);

    (void)hipMemsetAsync(counts, 0, NBT * sizeof(unsigned int), stream);

    proj_kernel<<<(NN + 255) / 256, 256, 0, stream>>>(x, W, h);

    dim3 gh((NE + H_EPB - 1) / H_EPB, NCH);
    bhist_kernel<<<gh, 256, 0, stream>>>(edge_rows, counts);

    bscan_kernel<<<1, 1024, 0, stream>>>(counts, starts, cursors);

    dim3 gb((NE + B_EPB - 1) / B_EPB, NCH);
    bin_kernel<<<gb, 256, 0, stream>>>(edge_rows, edge_cols, edge_vals, cursors, payA, payB);

    accum_kernel<<<NBT, 256, 0, stream>>>(starts, counts, payA, payB, h, b, out);
}